// Round 1
// baseline (432.559 us; speedup 1.0000x reference)
//
#include <hip/hip_runtime.h>
#include <hip/hip_bf16.h>
#include <math.h>

#define NBOX 19
#define NEDGE 171
#define TT 5
#define BATCH 2048

// Edge e with ROW=r starts at offset r*18 - r*(r-1)/2; e(r,c) = that + (c-r-1)
__device__ __forceinline__ int edge_index(int r, int c) {
    return r * (NBOX - 1) - (r * (r - 1)) / 2 + (c - r - 1);
}

// ---------------------------------------------------------------------------
// K1: per-batch dense normalized adjacency A[c][r] (19x19)
// ---------------------------------------------------------------------------
__global__ __launch_bounds__(192) void adj_kernel(
    const float* __restrict__ loc,   // (B,19,5)
    const int*   __restrict__ mask,  // (B,19) int32 0/1
    const float* __restrict__ past,  // (B,5,19,6)
    float* __restrict__ adj)         // (B,19,19)  A[c*19+r]
{
    int b = blockIdx.x;
    int tid = threadIdx.x;
    __shared__ float cx[NBOX], cy[NBOX], x0[NBOX], y0[NBOX], ndx[NBOX], ndy[NBOX];
    __shared__ int   mv[NBOX];
    __shared__ float w[NEDGE];
    __shared__ float dinv[NBOX];
    __shared__ float wmin_s, wmax_s;

    if (tid < NBOX) {
        const float* l = loc + ((size_t)b * NBOX + tid) * 5;
        cx[tid] = 0.5f * (l[1] + l[3]);
        cy[tid] = 0.5f * (l[2] + l[4]);
        const float* p0 = past + (((size_t)b * TT + 0) * NBOX + tid) * 6;
        const float* p4 = past + (((size_t)b * TT + (TT - 1)) * NBOX + tid) * 6;
        float cpx0 = (p0[3] - p0[1]) * 1280.0f, cpy0 = (p0[4] - p0[2]) * 720.0f;
        float cpx4 = (p4[3] - p4[1]) * 1280.0f, cpy4 = (p4[4] - p4[2]) * 720.0f;
        float dx = cpx4 - cpx0, dy = cpy4 - cpy0;
        float len = sqrtf(dx * dx + dy * dy);
        if (len == 0.0f) len = 1.0f;
        ndx[tid] = dx / len;
        ndy[tid] = dy / len;
        x0[tid] = cpx0;
        y0[tid] = cpy0;
        mv[tid] = mask[(size_t)b * NBOX + tid];
    }
    __syncthreads();

    float wv = 0.0f;
    int r = 0, c = 0;
    if (tid < NEDGE) {
        int rem = tid, rr = 0;
        while (rem >= NBOX - 1 - rr) { rem -= NBOX - 1 - rr; rr++; }
        r = rr; c = rr + 1 + rem;
        float ddx = cx[r] - cx[c], ddy = cy[r] - cy[c];
        float d = ddx * ddx + ddy * ddy;
        float ax = x0[r] + ndx[r] - x0[c] - ndx[c];
        float ay = y0[r] + ndy[r] - y0[c] - ndy[c];
        float d1 = sqrtf(ax * ax + ay * ay);
        float bx = x0[r] - x0[c], by = y0[r] - y0[c];
        float d2 = sqrtf(bx * bx + by * by);
        float md = d1 - d2;
        wv = expf(-(0.7f * d + 0.3f * md));
        if (!(mv[r] && mv[c])) wv = 0.0f;
        w[tid] = wv;
    }
    __syncthreads();

    if (tid == 0) {
        float mn = w[0], mx = w[0];
        for (int i = 1; i < NEDGE; i++) { mn = fminf(mn, w[i]); mx = fmaxf(mx, w[i]); }
        wmin_s = mn; wmax_s = mx;
    }
    __syncthreads();

    float inv_range = 1.0f / (wmax_s - wmin_s);
    if (tid < NEDGE) {
        w[tid] = (wv - wmin_s) * inv_range;
    }
    __syncthreads();

    // deg[c] = 1 (self loop) + sum over incoming edges (r,c), r<c
    if (tid < NBOX) {
        float s = 1.0f;
        for (int rr = 0; rr < tid; rr++) s += w[edge_index(rr, tid)];
        dinv[tid] = 1.0f / sqrtf(s);  // deg >= 1 always
    }
    __syncthreads();

    float* A = adj + (size_t)b * NBOX * NBOX;
    for (int idx = tid; idx < NBOX * NBOX; idx += blockDim.x) {
        int rr = idx % NBOX, cc = idx / NBOX;  // A[cc][rr]
        float v = 0.0f;
        if (rr == cc) v = dinv[rr] * dinv[rr];
        else if (rr < cc) v = w[edge_index(rr, cc)] * dinv[rr] * dinv[cc];
        A[idx] = v;
    }
}

// ---------------------------------------------------------------------------
// K2: layer 1 — H = sigmoid(A @ (X @ W1) + b1); X (19x512), W1 (512x256)
// one block per batch, 256 threads = one output column each
// ---------------------------------------------------------------------------
__global__ __launch_bounds__(256) void gcn1_kernel(
    const float* __restrict__ feat, const float* __restrict__ adj,
    const float* __restrict__ W1, const float* __restrict__ b1,
    float* __restrict__ Hout)
{
    int b = blockIdx.x;
    __shared__ float Xs[NBOX * 512];
    __shared__ float As[NBOX * NBOX];
    __shared__ float Ys[NBOX * 256];

    const float4* Xg = (const float4*)(feat + (size_t)b * NBOX * 512);
    for (int i = threadIdx.x; i < NBOX * 512 / 4; i += 256) ((float4*)Xs)[i] = Xg[i];
    for (int i = threadIdx.x; i < NBOX * NBOX; i += 256) As[i] = adj[(size_t)b * NBOX * NBOX + i];
    __syncthreads();

    int j = threadIdx.x;
    float acc[NBOX];
#pragma unroll
    for (int r = 0; r < NBOX; r++) acc[r] = 0.0f;

    for (int k = 0; k < 512; k += 4) {
        float w0 = W1[(k + 0) * 256 + j];
        float w1 = W1[(k + 1) * 256 + j];
        float w2 = W1[(k + 2) * 256 + j];
        float w3 = W1[(k + 3) * 256 + j];
#pragma unroll
        for (int r = 0; r < NBOX; r++) {
            float4 xv = *(const float4*)&Xs[r * 512 + k];
            acc[r] = fmaf(xv.x, w0, acc[r]);
            acc[r] = fmaf(xv.y, w1, acc[r]);
            acc[r] = fmaf(xv.z, w2, acc[r]);
            acc[r] = fmaf(xv.w, w3, acc[r]);
        }
    }
#pragma unroll
    for (int r = 0; r < NBOX; r++) Ys[r * 256 + j] = acc[r];
    __syncthreads();

    float bj = b1[j];
    float* Hg = Hout + (size_t)b * NBOX * 256;
    for (int cc = 0; cc < NBOX; cc++) {
        float s = bj;
#pragma unroll
        for (int rr = 0; rr < NBOX; rr++) s = fmaf(As[cc * NBOX + rr], Ys[rr * 256 + j], s);
        Hg[cc * 256 + j] = 1.0f / (1.0f + expf(-s));
    }
}

// ---------------------------------------------------------------------------
// K3: layer 2 — OUT = sigmoid(A @ (H @ W2) + b2); H (19x256), W2 (256x512)
// one block per batch, 256 threads, 2 output columns each (j, j+256)
// ---------------------------------------------------------------------------
__global__ __launch_bounds__(256) void gcn2_kernel(
    const float* __restrict__ Hin, const float* __restrict__ adj,
    const float* __restrict__ W2, const float* __restrict__ b2,
    float* __restrict__ out)
{
    int b = blockIdx.x;
    __shared__ float Xs[NBOX * 256];
    __shared__ float As[NBOX * NBOX];
    __shared__ float Ys[NBOX * 512];

    const float4* Xg = (const float4*)(Hin + (size_t)b * NBOX * 256);
    for (int i = threadIdx.x; i < NBOX * 256 / 4; i += 256) ((float4*)Xs)[i] = Xg[i];
    for (int i = threadIdx.x; i < NBOX * NBOX; i += 256) As[i] = adj[(size_t)b * NBOX * NBOX + i];
    __syncthreads();

    int j = threadIdx.x;
    float acc0[NBOX], acc1[NBOX];
#pragma unroll
    for (int r = 0; r < NBOX; r++) { acc0[r] = 0.0f; acc1[r] = 0.0f; }

    for (int k = 0; k < 256; k += 4) {
        float wa0 = W2[(k + 0) * 512 + j], wb0 = W2[(k + 0) * 512 + j + 256];
        float wa1 = W2[(k + 1) * 512 + j], wb1 = W2[(k + 1) * 512 + j + 256];
        float wa2 = W2[(k + 2) * 512 + j], wb2 = W2[(k + 2) * 512 + j + 256];
        float wa3 = W2[(k + 3) * 512 + j], wb3 = W2[(k + 3) * 512 + j + 256];
#pragma unroll
        for (int r = 0; r < NBOX; r++) {
            float4 xv = *(const float4*)&Xs[r * 256 + k];
            acc0[r] = fmaf(xv.x, wa0, acc0[r]);
            acc1[r] = fmaf(xv.x, wb0, acc1[r]);
            acc0[r] = fmaf(xv.y, wa1, acc0[r]);
            acc1[r] = fmaf(xv.y, wb1, acc1[r]);
            acc0[r] = fmaf(xv.z, wa2, acc0[r]);
            acc1[r] = fmaf(xv.z, wb2, acc1[r]);
            acc0[r] = fmaf(xv.w, wa3, acc0[r]);
            acc1[r] = fmaf(xv.w, wb3, acc1[r]);
        }
    }
#pragma unroll
    for (int r = 0; r < NBOX; r++) {
        Ys[r * 512 + j] = acc0[r];
        Ys[r * 512 + j + 256] = acc1[r];
    }
    __syncthreads();

    float bj0 = b2[j], bj1 = b2[j + 256];
    float* Og = out + (size_t)b * NBOX * 512;
    for (int cc = 0; cc < NBOX; cc++) {
        float s0 = bj0, s1 = bj1;
#pragma unroll
        for (int rr = 0; rr < NBOX; rr++) {
            float a = As[cc * NBOX + rr];
            s0 = fmaf(a, Ys[rr * 512 + j], s0);
            s1 = fmaf(a, Ys[rr * 512 + j + 256], s1);
        }
        Og[cc * 512 + j] = 1.0f / (1.0f + expf(-s0));
        Og[cc * 512 + j + 256] = 1.0f / (1.0f + expf(-s1));
    }
}

extern "C" void kernel_launch(void* const* d_in, const int* in_sizes, int n_in,
                              void* d_out, int out_size, void* d_ws, size_t ws_size,
                              hipStream_t stream) {
    const float* loc  = (const float*)d_in[0];
    const float* feat = (const float*)d_in[1];
    const int*   mask = (const int*)d_in[2];
    const float* past = (const float*)d_in[3];
    const float* W1   = (const float*)d_in[4];
    const float* b1   = (const float*)d_in[5];
    const float* W2   = (const float*)d_in[6];
    const float* b2   = (const float*)d_in[7];
    float* out = (float*)d_out;

    float* adj = (float*)d_ws;                       // 2048*361 floats
    float* H   = adj + (size_t)BATCH * NBOX * NBOX;  // 2048*19*256 floats

    adj_kernel<<<BATCH, 192, 0, stream>>>(loc, mask, past, adj);
    gcn1_kernel<<<BATCH, 256, 0, stream>>>(feat, adj, W1, b1, H);
    gcn2_kernel<<<BATCH, 256, 0, stream>>>(H, adj, W2, b2, out);
}

// Round 2
// 128.555 us; speedup vs baseline: 3.3648x; 3.3648x over previous
//
#include <hip/hip_runtime.h>
#include <hip/hip_bf16.h>
#include <math.h>

#define NBOX 19
#define NEDGE 171
#define TT 5
#define BATCH 2048
#define MROWS (BATCH * NBOX)   // 38912

typedef __attribute__((ext_vector_type(8))) short short8v;
typedef __attribute__((ext_vector_type(4))) float f32x4;

static __device__ __forceinline__ ushort f2bf(float f) {
    __hip_bfloat16 h = __float2bfloat16(f);
    return *reinterpret_cast<ushort*>(&h);
}

__device__ __forceinline__ int edge_index(int r, int c) {
    return r * (NBOX - 1) - (r * (r - 1)) / 2 + (c - r - 1);
}

// ---------------------------------------------------------------------------
// K1: per-batch dense normalized adjacency A[c][r] (19x19) — unchanged (works)
// ---------------------------------------------------------------------------
__global__ __launch_bounds__(192) void adj_kernel(
    const float* __restrict__ loc,
    const int*   __restrict__ mask,
    const float* __restrict__ past,
    float* __restrict__ adj)
{
    int b = blockIdx.x;
    int tid = threadIdx.x;
    __shared__ float cx[NBOX], cy[NBOX], x0[NBOX], y0[NBOX], ndx[NBOX], ndy[NBOX];
    __shared__ int   mv[NBOX];
    __shared__ float w[NEDGE];
    __shared__ float dinv[NBOX];
    __shared__ float wmin_s, wmax_s;

    if (tid < NBOX) {
        const float* l = loc + ((size_t)b * NBOX + tid) * 5;
        cx[tid] = 0.5f * (l[1] + l[3]);
        cy[tid] = 0.5f * (l[2] + l[4]);
        const float* p0 = past + (((size_t)b * TT + 0) * NBOX + tid) * 6;
        const float* p4 = past + (((size_t)b * TT + (TT - 1)) * NBOX + tid) * 6;
        float cpx0 = (p0[3] - p0[1]) * 1280.0f, cpy0 = (p0[4] - p0[2]) * 720.0f;
        float cpx4 = (p4[3] - p4[1]) * 1280.0f, cpy4 = (p4[4] - p4[2]) * 720.0f;
        float dx = cpx4 - cpx0, dy = cpy4 - cpy0;
        float len = sqrtf(dx * dx + dy * dy);
        if (len == 0.0f) len = 1.0f;
        ndx[tid] = dx / len;
        ndy[tid] = dy / len;
        x0[tid] = cpx0;
        y0[tid] = cpy0;
        mv[tid] = mask[(size_t)b * NBOX + tid];
    }
    __syncthreads();

    float wv = 0.0f;
    if (tid < NEDGE) {
        int rem = tid, rr = 0;
        while (rem >= NBOX - 1 - rr) { rem -= NBOX - 1 - rr; rr++; }
        int r = rr, c = rr + 1 + rem;
        float ddx = cx[r] - cx[c], ddy = cy[r] - cy[c];
        float d = ddx * ddx + ddy * ddy;
        float ax = x0[r] + ndx[r] - x0[c] - ndx[c];
        float ay = y0[r] + ndy[r] - y0[c] - ndy[c];
        float d1 = sqrtf(ax * ax + ay * ay);
        float bx = x0[r] - x0[c], by = y0[r] - y0[c];
        float d2 = sqrtf(bx * bx + by * by);
        float md = d1 - d2;
        wv = expf(-(0.7f * d + 0.3f * md));
        if (!(mv[r] && mv[c])) wv = 0.0f;
        w[tid] = wv;
    }
    __syncthreads();

    if (tid == 0) {
        float mn = w[0], mx = w[0];
        for (int i = 1; i < NEDGE; i++) { mn = fminf(mn, w[i]); mx = fmaxf(mx, w[i]); }
        wmin_s = mn; wmax_s = mx;
    }
    __syncthreads();

    float inv_range = 1.0f / (wmax_s - wmin_s);
    if (tid < NEDGE) w[tid] = (wv - wmin_s) * inv_range;
    __syncthreads();

    if (tid < NBOX) {
        float s = 1.0f;
        for (int rr = 0; rr < tid; rr++) s += w[edge_index(rr, tid)];
        dinv[tid] = 1.0f / sqrtf(s);
    }
    __syncthreads();

    float* A = adj + (size_t)b * NBOX * NBOX;
    for (int idx = tid; idx < NBOX * NBOX; idx += blockDim.x) {
        int rr = idx % NBOX, cc = idx / NBOX;
        float v = 0.0f;
        if (rr == cc) v = dinv[rr] * dinv[rr];
        else if (rr < cc) v = w[edge_index(rr, cc)] * dinv[rr] * dinv[cc];
        A[idx] = v;
    }
}

// ---------------------------------------------------------------------------
// K2: transpose + cvt weights: dst[n*K+k] = bf16(src[k*N+n])
// ---------------------------------------------------------------------------
__global__ void packT_kernel(const float* __restrict__ src, ushort* __restrict__ dst,
                             int K, int N)
{
    int total = K * N;
    for (int idx = blockIdx.x * blockDim.x + threadIdx.x; idx < total;
         idx += gridDim.x * blockDim.x) {
        int n = idx / K, k = idx % K;
        dst[idx] = f2bf(src[(size_t)k * N + n]);
    }
}

// ---------------------------------------------------------------------------
// K3: bf16 MFMA GEMM  Y[M][N] = A[M][K] @ BT[N][K]^T
// BM=128, BN=64, BK=64; 256 threads = 4 waves (2x2); wave tile 64x32
// AF32=1: A is fp32 (converted during staging); AF32=0: A is bf16 (ushort)
// ---------------------------------------------------------------------------
template<int AF32>
__global__ __launch_bounds__(256) void gemm_bf16_kernel(
    const void* __restrict__ Ag_, const ushort* __restrict__ BT,
    float* __restrict__ Y, int K, int N)
{
    constexpr int BM = 128, BN = 64, BK = 64;
    __shared__ __align__(16) ushort As[BM * BK];  // swizzled, row stride 128B
    __shared__ __align__(16) ushort Bs[BN * BK];  // swizzled, row stride 128B

    const int tid = threadIdx.x;
    const int lane = tid & 63, wid = tid >> 6;
    const int wm = wid >> 1, wn = wid & 1;
    const int bM = blockIdx.x, bN = blockIdx.y;

    f32x4 acc[4][2];
#pragma unroll
    for (int fm = 0; fm < 4; fm++)
#pragma unroll
        for (int fn = 0; fn < 2; fn++)
            acc[fm][fn] = (f32x4){0.0f, 0.0f, 0.0f, 0.0f};

    for (int k0 = 0; k0 < K; k0 += BK) {
        __syncthreads();
        // ---- stage A tile (BM x BK) ----
        if constexpr (AF32) {
            const float* Ag = (const float*)Ag_;
            int r = tid >> 4, g = tid & 15;   // 16 lanes cover one row (64 fp32)
#pragma unroll
            for (int p = 0; p < 8; p++) {
                int row = r + p * 16;
                const float4 v = *(const float4*)(Ag + ((size_t)(bM * BM + row)) * K + k0 + g * 4);
                ushort4 h;
                h.x = f2bf(v.x); h.y = f2bf(v.y); h.z = f2bf(v.z); h.w = f2bf(v.w);
                int boff = (row * 128 + g * 8) ^ ((row & 7) << 4);
                *(ushort4*)((char*)As + boff) = h;
            }
        } else {
            const ushort* Ag = (const ushort*)Ag_;
            int r = tid >> 3, g = tid & 7;    // 8 lanes cover one row (64 bf16)
#pragma unroll
            for (int p = 0; p < 4; p++) {
                int row = r + p * 32;
                const int4 v = *(const int4*)(Ag + ((size_t)(bM * BM + row)) * K + k0 + g * 8);
                int boff = (row * 128 + g * 16) ^ ((row & 7) << 4);
                *(int4*)((char*)As + boff) = v;
            }
        }
        // ---- stage B tile (BN x BK) from BT[N][K] ----
        {
            int r = tid >> 3, g = tid & 7;
#pragma unroll
            for (int p = 0; p < 2; p++) {
                int n = r + p * 32;
                const int4 v = *(const int4*)(BT + ((size_t)(bN * BN + n)) * K + k0 + g * 8);
                int boff = (n * 128 + g * 16) ^ ((n & 7) << 4);
                *(int4*)((char*)Bs + boff) = v;
            }
        }
        __syncthreads();

        // ---- compute: 2 k-slices of 32 ----
#pragma unroll
        for (int ks = 0; ks < 2; ks++) {
            short8v a[4], bb[2];
#pragma unroll
            for (int fm = 0; fm < 4; fm++) {
                int row = wm * 64 + fm * 16 + (lane & 15);
                int boff = (row * 128 + ks * 64 + (lane >> 4) * 16) ^ ((row & 7) << 4);
                a[fm] = *(short8v*)((char*)As + boff);
            }
#pragma unroll
            for (int fn = 0; fn < 2; fn++) {
                int n = wn * 32 + fn * 16 + (lane & 15);
                int boff = (n * 128 + ks * 64 + (lane >> 4) * 16) ^ ((n & 7) << 4);
                bb[fn] = *(short8v*)((char*)Bs + boff);
            }
#pragma unroll
            for (int fm = 0; fm < 4; fm++)
#pragma unroll
                for (int fn = 0; fn < 2; fn++)
                    acc[fm][fn] = __builtin_amdgcn_mfma_f32_16x16x32_bf16(
                        a[fm], bb[fn], acc[fm][fn], 0, 0, 0);
        }
    }

    // ---- epilogue: C/D layout col=lane&15, row=(lane>>4)*4+j ----
#pragma unroll
    for (int fm = 0; fm < 4; fm++) {
        int grow0 = bM * BM + wm * 64 + fm * 16 + (lane >> 4) * 4;
#pragma unroll
        for (int fn = 0; fn < 2; fn++) {
            int gcol = bN * BN + wn * 32 + fn * 16 + (lane & 15);
#pragma unroll
            for (int j = 0; j < 4; j++) {
                Y[(size_t)(grow0 + j) * N + gcol] = acc[fm][fn][j];
            }
        }
    }
}

// ---------------------------------------------------------------------------
// K4: agg1 — H = bf16(sigmoid(A @ Y1 + b1)), N=256
// ---------------------------------------------------------------------------
__global__ __launch_bounds__(256) void agg1_kernel(
    const float* __restrict__ Y1, const float* __restrict__ adj,
    const float* __restrict__ b1, ushort* __restrict__ H)
{
    int b = blockIdx.x, j = threadIdx.x;
    __shared__ float As[NBOX * NBOX];
    for (int i = j; i < NBOX * NBOX; i += 256) As[i] = adj[(size_t)b * NBOX * NBOX + i];
    __syncthreads();

    const float* Yb = Y1 + (size_t)b * NBOX * 256;
    float y[NBOX];
#pragma unroll
    for (int r = 0; r < NBOX; r++) y[r] = Yb[r * 256 + j];
    float bj = b1[j];
    ushort* Hb = H + (size_t)b * NBOX * 256;
#pragma unroll
    for (int cc = 0; cc < NBOX; cc++) {
        float s = bj;
#pragma unroll
        for (int r = 0; r < NBOX; r++) s = fmaf(As[cc * NBOX + r], y[r], s);
        Hb[cc * 256 + j] = f2bf(1.0f / (1.0f + expf(-s)));
    }
}

// ---------------------------------------------------------------------------
// K5: agg2 — out = sigmoid(A @ Y2 + b2), N=512, IN-PLACE in d_out
// (thread j reads all 19 rows of cols {j, j+256} into regs, then writes)
// ---------------------------------------------------------------------------
__global__ __launch_bounds__(256) void agg2_kernel(
    const float* __restrict__ adj, const float* __restrict__ b2, float* Y)
{
    int b = blockIdx.x, j = threadIdx.x;
    __shared__ float As[NBOX * NBOX];
    for (int i = j; i < NBOX * NBOX; i += 256) As[i] = adj[(size_t)b * NBOX * NBOX + i];
    __syncthreads();

    float* Yb = Y + (size_t)b * NBOX * 512;
    float y0[NBOX], y1[NBOX];
#pragma unroll
    for (int r = 0; r < NBOX; r++) {
        y0[r] = Yb[r * 512 + j];
        y1[r] = Yb[r * 512 + j + 256];
    }
    float bj0 = b2[j], bj1 = b2[j + 256];
#pragma unroll
    for (int cc = 0; cc < NBOX; cc++) {
        float s0 = bj0, s1 = bj1;
#pragma unroll
        for (int r = 0; r < NBOX; r++) {
            float a = As[cc * NBOX + r];
            s0 = fmaf(a, y0[r], s0);
            s1 = fmaf(a, y1[r], s1);
        }
        Yb[cc * 512 + j]       = 1.0f / (1.0f + expf(-s0));
        Yb[cc * 512 + j + 256] = 1.0f / (1.0f + expf(-s1));
    }
}

extern "C" void kernel_launch(void* const* d_in, const int* in_sizes, int n_in,
                              void* d_out, int out_size, void* d_ws, size_t ws_size,
                              hipStream_t stream) {
    const float* loc  = (const float*)d_in[0];
    const float* feat = (const float*)d_in[1];
    const int*   mask = (const int*)d_in[2];
    const float* past = (const float*)d_in[3];
    const float* W1   = (const float*)d_in[4];
    const float* b1   = (const float*)d_in[5];
    const float* W2   = (const float*)d_in[6];
    const float* b2   = (const float*)d_in[7];

    // workspace layout (~23.4 MB)
    float*  adj = (float*)d_ws;                               // 2048*361 f32
    ushort* W1T = (ushort*)(adj + (size_t)BATCH * NBOX * NBOX); // 256*512 bf16
    ushort* W2T = W1T + 256 * 512;                            // 512*256 bf16
    ushort* H   = W2T + 512 * 256;                            // 38912*256 bf16

    // Y1 (38912x256 f32) and Y2 (38912x512 f32) live in d_out as scratch;
    // agg2 overwrites d_out fully with the final result each call.
    float* Y1 = (float*)d_out;
    float* Y2 = (float*)d_out;

    adj_kernel<<<BATCH, 192, 0, stream>>>(loc, mask, past, adj);
    packT_kernel<<<512, 256, 0, stream>>>(W1, W1T, 512, 256);
    packT_kernel<<<512, 256, 0, stream>>>(W2, W2T, 256, 512);

    gemm_bf16_kernel<1><<<dim3(MROWS / 128, 256 / 64), 256, 0, stream>>>(
        feat, W1T, Y1, 512, 256);
    agg1_kernel<<<BATCH, 256, 0, stream>>>(Y1, adj, b1, H);
    gemm_bf16_kernel<0><<<dim3(MROWS / 128, 512 / 64), 256, 0, stream>>>(
        H, W2T, Y2, 256, 512);
    agg2_kernel<<<BATCH, 256, 0, stream>>>(adj, b2, Y2);
}